// Round 2
// baseline (1567.147 us; speedup 1.0000x reference)
//
#include <hip/hip_runtime.h>

namespace {
constexpr int Bn  = 8;
constexpr int Nn  = 4096;
constexpr int KKn = 20;
constexpr int C1n = 64;
constexpr int C2n = 128;
constexpr int C3n = 256;
constexpr float EPSc = 1e-5f;
constexpr float INV_CNT1 = 1.0f / (8.0f * 4096.0f * 20.0f);  // B*N*k
constexpr float INV_CNT3 = 1.0f / (8.0f * 4096.0f);          // B*N
constexpr float INFK = 3.0e38f;
constexpr size_t IDX_N = (size_t)Bn * Nn * KKn;              // 655360
}

#define DEVI __device__ __forceinline__

// ---------------------------------------------------------------------------
// K0: zero stat accumulators: statK(64) + Mbuf(8*4096) + S64(64) + AB2(256) + st3(512)
__global__ void k_zero(float* __restrict__ p) {
    const int i = blockIdx.x * 256 + threadIdx.x;
    if (i < 33664) p[i] = 0.0f;
}

// sorted top-5 insert, (d) key (index ties measure-zero for random data)
DEVI void ins5(float d, int j, float& m0, float& m1, float& m2, float& m3, float& m4,
               int& j0, int& j1, int& j2, int& j3, int& j4) {
    if (d < m4) {
        if (d < m3) {
            m4 = m3; j4 = j3;
            if (d < m2) {
                m3 = m2; j3 = j2;
                if (d < m1) {
                    m2 = m1; j2 = j1;
                    if (d < m0) { m1 = m0; j1 = j0; m0 = d; j0 = j; }
                    else        { m1 = d;  j1 = j; }
                } else { m2 = d; j2 = j; }
            } else { m3 = d; j3 = j; }
        } else { m4 = d; j4 = j; }
    }
}

// ---------------------------------------------------------------------------
// K1: kNN top-20, 16 lanes per row (4 rows/wave), per-lane top-5 + rescan.
// Fused channel-independent conv1 stats: S6 = sum(e), M21 = sum(e e^T) upper.
__global__ __launch_bounds__(256) void k_knn(const float* __restrict__ x,
                                             int* __restrict__ idxout,
                                             float* __restrict__ statK) {
    __shared__ float xs[Nn], ys[Nn], zs[Nn];
    __shared__ int   lidx[16][KKn];
    __shared__ float red[4][27];
    const int b = blockIdx.y;
    const float* xb = x + (size_t)b * 3 * Nn;
    for (int t = threadIdx.x; t < Nn; t += 256) {
        xs[t] = xb[t]; ys[t] = xb[Nn + t]; zs[t] = xb[2 * Nn + t];
    }
    const int lane = threadIdx.x & 63;
    const int wave = threadIdx.x >> 6;
    const int grp  = lane >> 4;
    const int gl   = lane & 15;
    float S[6] = {};
    float M[21] = {};
    __syncthreads();

    for (int pass = 0; pass < 2; ++pass) {
        const int row = blockIdx.x * 32 + pass * 16 + wave * 4 + grp;
        const float px = xs[row], py = ys[row], pz = zs[row];
        float m0 = INFK, m1 = INFK, m2 = INFK, m3 = INFK, m4 = INFK;
        int   j0 = 0, j1 = 0, j2 = 0, j3 = 0, j4 = 0;
        #pragma unroll 4
        for (int t = 0; t < 256; ++t) {
            const int j = t * 16 + gl;
            const float dx = px - xs[j], dy = py - ys[j], dz = pz - zs[j];
            const float d = fmaf(dx, dx, fmaf(dy, dy, dz * dz));
            ins5(d, j, m0, m1, m2, m3, m4, j0, j1, j2, j3, j4);
        }
        float lastd = -INFK; int lastj = -1;
        for (int s = 0; s < KKn; ++s) {
            if (__any(m0 >= INFK)) {            // rare: lane exhausted its 5
                if (m0 >= INFK) {
                    m0 = m1 = m2 = m3 = m4 = INFK; j0 = j1 = j2 = j3 = j4 = 0;
                    #pragma unroll 1
                    for (int t = 0; t < 256; ++t) {
                        const int j = t * 16 + gl;
                        const float dx = px - xs[j], dy = py - ys[j], dz = pz - zs[j];
                        const float d = fmaf(dx, dx, fmaf(dy, dy, dz * dz));
                        if (d > lastd || (d == lastd && j > lastj))
                            ins5(d, j, m0, m1, m2, m3, m4, j0, j1, j2, j3, j4);
                    }
                }
            }
            float bd = m0; int bj = j0;
            #pragma unroll
            for (int off = 1; off < 16; off <<= 1) {
                const float od = __shfl_xor(bd, off);
                const int   oj = __shfl_xor(bj, off);
                if (od < bd || (od == bd && oj < bj)) { bd = od; bj = oj; }
            }
            if (gl == 0) lidx[wave * 4 + grp][s] = bj;
            if (bd == m0 && bj == j0 && m0 < INFK) {   // this lane won: pop
                lastd = m0; lastj = j0;
                m0 = m1; j0 = j1; m1 = m2; j1 = j2; m2 = m3; j2 = j3;
                m3 = m4; j3 = j4; m4 = INFK;
            }
        }
        // stats + idx writeout: 80 winners for this wave's 4 rows
        #pragma unroll
        for (int rep = 0; rep < 2; ++rep) {
            const int w = rep * 64 + lane;
            if (w < 80) {
                const int r  = (w * 3277) >> 16;       // w / 20
                const int kk = w - r * 20;
                const int rowg = blockIdx.x * 32 + pass * 16 + wave * 4 + r;
                const int j = lidx[wave * 4 + r][kk];
                const float cx = xs[rowg], cy = ys[rowg], cz = zs[rowg];
                const float e[6] = { xs[j] - cx, ys[j] - cy, zs[j] - cz, cx, cy, cz };
                int q = 0;
                #pragma unroll
                for (int a = 0; a < 6; ++a) {
                    S[a] += e[a];
                    #pragma unroll
                    for (int bb = a; bb < 6; ++bb) { M[q] = fmaf(e[a], e[bb], M[q]); ++q; }
                }
                idxout[(size_t)(b * Nn + rowg) * KKn + kk] = j;
            }
        }
    }
    // reduce 27 accumulators: wave butterfly, then cross-wave + atomic
    #pragma unroll
    for (int i = 0; i < 6; ++i) {
        float t = S[i];
        #pragma unroll
        for (int off = 1; off < 64; off <<= 1) t += __shfl_xor(t, off);
        S[i] = t;
    }
    #pragma unroll
    for (int i = 0; i < 21; ++i) {
        float t = M[i];
        #pragma unroll
        for (int off = 1; off < 64; off <<= 1) t += __shfl_xor(t, off);
        M[i] = t;
    }
    if (lane == 0) {
        #pragma unroll
        for (int i = 0; i < 6; ++i) red[wave][i] = S[i];
        #pragma unroll
        for (int i = 0; i < 21; ++i) red[wave][6 + i] = M[i];
    }
    __syncthreads();
    if (threadIdx.x < 27) {
        const int i = threadIdx.x;
        atomicAdd(&statK[i], red[0][i] + red[1][i] + red[2][i] + red[3][i]);
    }
}

// ---------------------------------------------------------------------------
// derive BN1 coefficients for channel o from S6/M21
DEVI void bn1_coef(const float* __restrict__ statK, const float* __restrict__ W1,
                   const float* __restrict__ g1, const float* __restrict__ b1,
                   int o, float& a1, float& be1, float* w1r) {
    #pragma unroll
    for (int c = 0; c < 6; ++c) w1r[c] = W1[o * 6 + c];
    float s1 = 0.f, q1 = 0.f;
    #pragma unroll
    for (int a = 0; a < 6; ++a) s1 = fmaf(w1r[a], statK[a], s1);
    int qi = 6;
    #pragma unroll
    for (int a = 0; a < 6; ++a) {
        #pragma unroll
        for (int bb = a; bb < 6; ++bb) {
            const float coef = (a == bb ? 1.f : 2.f) * w1r[a] * w1r[bb];
            q1 = fmaf(coef, statK[qi], q1); ++qi;
        }
    }
    const float mu  = s1 * INV_CNT1;
    const float var = q1 * INV_CNT1 - mu * mu;
    const float rs  = rsqrtf(var + EPSc);
    a1  = rs * g1[o];
    be1 = fmaf(-mu, a1, b1[o]);
}

// shared phase-1: recompute h1_hat for 8 points into LDS [160][64]
template <bool POOL>
DEVI void conv1_phase1(const float* __restrict__ x, const int* __restrict__ idx,
                       float a1, float be1, const float* w1r,
                       float* __restrict__ cat, int b, int n0, int tid,
                       float (*hhat)[64], float* sAcc) {
    const int o = tid & 63;
    const int wave = tid >> 6;
    const float* xb = x + (size_t)b * 3 * Nn;
    #pragma unroll
    for (int pp = 0; pp < 2; ++pp) {
        const int p = wave * 2 + pp;
        const int n = n0 + p;
        const float cx = xb[n], cy = xb[Nn + n], cz = xb[2 * Nn + n];
        const float t2 = fmaf(w1r[3], cx, fmaf(w1r[4], cy, w1r[5] * cz));
        float hk[KKn];
        #pragma unroll
        for (int kk = 0; kk < KKn; ++kk) {
            const int j = idx[(size_t)(b * Nn + n) * KKn + kk];
            const float dx = xb[j] - cx, dy = xb[Nn + j] - cy, dz = xb[2 * Nn + j] - cz;
            float h = fmaf(w1r[0], dx, fmaf(w1r[1], dy, fmaf(w1r[2], dz, t2)));
            h = fmaxf(fmaf(h, a1, be1), 0.0f);
            hk[kk] = h;
            hhat[p * KKn + kk][o] = h;
            if (POOL) *sAcc += h;
        }
        if (POOL) {
            float mx = hk[0];
            #pragma unroll
            for (int kk = 1; kk < KKn; ++kk) mx = fmaxf(mx, hk[kk]);
            float se = 0.0f, sw = 0.0f;
            #pragma unroll
            for (int kk = 0; kk < KKn; ++kk) {
                const float e = __expf(hk[kk] - mx);
                se += e;
                sw = fmaf(hk[kk], e, sw);
            }
            cat[(size_t)(b * Nn + n) * 192 + o] = sw / se;
        }
    }
}

// ---------------------------------------------------------------------------
// K2: phase1 (+x1 pool) over 32 points, accumulate M2 = sum(h h^T) and S64
__global__ __launch_bounds__(256) void k_conv1(const float* __restrict__ x,
        const int* __restrict__ idx,
        const float* __restrict__ W1, const float* __restrict__ g1, const float* __restrict__ b1,
        const float* __restrict__ statK,
        float* __restrict__ Mbuf, float* __restrict__ S64,
        float* __restrict__ cat) {
    __shared__ float hhat[160][64];
    __shared__ float redS[4][64];
    const int tid = threadIdx.x;
    const int b  = blockIdx.x >> 7;
    const int n0 = (blockIdx.x & 127) * 32;
    float a1, be1, w1r[6];
    bn1_coef(statK, W1, g1, b1, tid & 63, a1, be1, w1r);
    const int abase = (tid >> 4) * 4;
    const int bbase = (tid & 15) * 4;
    float acc[4][4] = {};
    float sAcc = 0.f;
    for (int pass = 0; pass < 4; ++pass) {
        if (pass) __syncthreads();
        conv1_phase1<true>(x, idx, a1, be1, w1r, cat, b, n0 + pass * 8, tid, hhat, &sAcc);
        __syncthreads();
        #pragma unroll 2
        for (int p = 0; p < 160; ++p) {
            const float4 hav = *reinterpret_cast<const float4*>(&hhat[p][abase]);
            const float4 hbv = *reinterpret_cast<const float4*>(&hhat[p][bbase]);
            const float ha_[4] = { hav.x, hav.y, hav.z, hav.w };
            const float hb_[4] = { hbv.x, hbv.y, hbv.z, hbv.w };
            #pragma unroll
            for (int i = 0; i < 4; ++i)
                #pragma unroll
                for (int jj = 0; jj < 4; ++jj)
                    acc[i][jj] = fmaf(ha_[i], hb_[jj], acc[i][jj]);
        }
    }
    float* Mb = Mbuf + ((blockIdx.x & 7) << 12);
    #pragma unroll
    for (int i = 0; i < 4; ++i)
        #pragma unroll
        for (int jj = 0; jj < 4; ++jj)
            atomicAdd(&Mb[(abase + i) * 64 + bbase + jj], acc[i][jj]);
    redS[tid >> 6][tid & 63] = sAcc;
    __syncthreads();
    if (tid < 64)
        atomicAdd(&S64[tid], redS[0][tid] + redS[1][tid] + redS[2][tid] + redS[3][tid]);
}

// ---------------------------------------------------------------------------
// K3: finalize conv2 BN coefficients: a2/be2 from W2^T M2 W2 and W2 S64
__global__ __launch_bounds__(256) void k_stats2(const float* __restrict__ Mbuf,
        const float* __restrict__ S64, const float* __restrict__ W2,
        const float* __restrict__ g2, const float* __restrict__ b2,
        float* __restrict__ AB2) {
    __shared__ float ms[4096];
    __shared__ float w2s[16][64];
    const int tid = threadIdx.x;
    for (int e = tid; e < 4096; e += 256) {
        float t = 0.f;
        #pragma unroll
        for (int r = 0; r < 8; ++r) t += Mbuf[r * 4096 + e];
        ms[e] = t;
    }
    const int c0 = blockIdx.x * 16;
    for (int t = tid; t < 16 * 64; t += 256)
        w2s[t >> 6][t & 63] = W2[(c0 + (t >> 6)) * 64 + (t & 63)];
    __syncthreads();
    const int cl = tid >> 4;
    const int gl = tid & 15;
    const int c  = c0 + cl;
    float q2 = 0.f, s2 = 0.f;
    #pragma unroll
    for (int ai = 0; ai < 4; ++ai) {
        const int a = gl * 4 + ai;
        float inner = 0.f;
        for (int bq = 0; bq < 64; ++bq) {
            const int bb = (bq + 4 * gl) & 63;     // rotate to dodge bank conflicts
            inner = fmaf(w2s[cl][bb], ms[a * 64 + bb], inner);
        }
        q2 = fmaf(w2s[cl][a], inner, q2);
        s2 = fmaf(w2s[cl][a], S64[a], s2);
    }
    #pragma unroll
    for (int off = 1; off < 16; off <<= 1) {
        q2 += __shfl_xor(q2, off);
        s2 += __shfl_xor(s2, off);
    }
    if (gl == 0) {
        const float mu  = s2 * INV_CNT1;
        const float var = q2 * INV_CNT1 - mu * mu;
        const float rs  = rsqrtf(var + EPSc);
        const float a2  = rs * g2[c];
        AB2[c]         = a2;
        AB2[C2n + c]   = fmaf(-mu, a2, b2[c]);
    }
}

// ---------------------------------------------------------------------------
// K4: phase1 again, then conv2 + BN + relu + attn-pool -> cat[:, 64:192]
__global__ __launch_bounds__(256) void k_conv2(const float* __restrict__ x,
        const int* __restrict__ idx,
        const float* __restrict__ W1, const float* __restrict__ g1, const float* __restrict__ b1,
        const float* __restrict__ W2, const float* __restrict__ AB2,
        const float* __restrict__ statK,
        float* __restrict__ cat) {
    __shared__ float hhat[160][64];
    __shared__ float w2s[C2n][68];
    const int tid = threadIdx.x;
    const int b  = blockIdx.x >> 9;
    const int n0 = (blockIdx.x & 511) * 8;
    float a1, be1, w1r[6];
    bn1_coef(statK, W1, g1, b1, tid & 63, a1, be1, w1r);
    for (int t = tid; t < C2n * C1n; t += 256) w2s[t >> 6][t & 63] = W2[t];
    conv1_phase1<false>(x, idx, a1, be1, w1r, cat, b, n0, tid, hhat, nullptr);
    __syncthreads();

    const int q = tid & 31;
    const int p = tid >> 5;
    const int n = n0 + p;
    float a2[4], be2[4];
    #pragma unroll
    for (int m = 0; m < 4; ++m) {
        const int ch = q + 32 * m;
        a2[m]  = AB2[ch];
        be2[m] = AB2[C2n + ch];
    }
    float acc[4][KKn] = {};
    for (int oc = 0; oc < 16; ++oc) {
        float4 w[4];
        #pragma unroll
        for (int m = 0; m < 4; ++m)
            w[m] = *reinterpret_cast<const float4*>(&w2s[q + 32 * m][oc * 4]);
        #pragma unroll
        for (int kk = 0; kk < KKn; ++kk) {
            const float4 h = *reinterpret_cast<const float4*>(&hhat[p * KKn + kk][oc * 4]);
            #pragma unroll
            for (int m = 0; m < 4; ++m) {
                acc[m][kk] = fmaf(w[m].x, h.x, acc[m][kk]);
                acc[m][kk] = fmaf(w[m].y, h.y, acc[m][kk]);
                acc[m][kk] = fmaf(w[m].z, h.z, acc[m][kk]);
                acc[m][kk] = fmaf(w[m].w, h.w, acc[m][kk]);
            }
        }
    }
    #pragma unroll
    for (int m = 0; m < 4; ++m) {
        float v[KKn];
        float mx = 0.0f;
        #pragma unroll
        for (int kk = 0; kk < KKn; ++kk) {
            v[kk] = fmaxf(fmaf(acc[m][kk], a2[m], be2[m]), 0.0f);
            mx = fmaxf(mx, v[kk]);
        }
        float se = 0.0f, sw = 0.0f;
        #pragma unroll
        for (int kk = 0; kk < KKn; ++kk) {
            const float e = __expf(v[kk] - mx);
            se += e;
            sw = fmaf(v[kk], e, sw);
        }
        cat[(size_t)(b * Nn + n) * 192 + 64 + q + 32 * m] = sw / se;
    }
}

// ---------------------------------------------------------------------------
// K5: FC 256<-192 over cat, write pre-BN to d_out, accumulate stats3
__global__ __launch_bounds__(256) void k_fc(const float* __restrict__ cat,
        const float* __restrict__ W3,
        float* __restrict__ stats3, float* __restrict__ out) {
    __shared__ float w3s[C3n][52];
    __shared__ float ctf[32 * 192];
    const int tid = threadIdx.x;
    const int b  = blockIdx.x >> 7;
    const int n0 = (blockIdx.x & 127) * 32;
    const size_t base = (size_t)(b * Nn + n0) * 192;
    for (int t = tid; t < 32 * 192; t += 256) ctf[t] = cat[base + t];
    const int o3a = tid & 127;
    const int ph  = tid >> 7;
    float acc[2][16] = {};
    for (int ch = 0; ch < 4; ++ch) {
        __syncthreads();
        for (int t = tid; t < 256 * 48; t += 256) {
            const int row = t / 48, col = t - row * 48;
            w3s[row][col] = W3[row * 192 + ch * 48 + col];
        }
        __syncthreads();
        for (int c4 = 0; c4 < 12; ++c4) {
            const int c = c4 * 4;
            const float4 wA = *reinterpret_cast<const float4*>(&w3s[o3a][c]);
            const float4 wB = *reinterpret_cast<const float4*>(&w3s[o3a + 128][c]);
            #pragma unroll
            for (int p = 0; p < 16; ++p) {
                const int gp = ph * 16 + p;
                const float4 h = *reinterpret_cast<const float4*>(&ctf[gp * 192 + ch * 48 + c]);
                acc[0][p] = fmaf(wA.x, h.x, acc[0][p]);
                acc[0][p] = fmaf(wA.y, h.y, acc[0][p]);
                acc[0][p] = fmaf(wA.z, h.z, acc[0][p]);
                acc[0][p] = fmaf(wA.w, h.w, acc[0][p]);
                acc[1][p] = fmaf(wB.x, h.x, acc[1][p]);
                acc[1][p] = fmaf(wB.y, h.y, acc[1][p]);
                acc[1][p] = fmaf(wB.z, h.z, acc[1][p]);
                acc[1][p] = fmaf(wB.w, h.w, acc[1][p]);
            }
        }
    }
    #pragma unroll
    for (int half = 0; half < 2; ++half) {
        const int o3 = o3a + half * 128;
        float s = 0.0f, qq = 0.0f;
        #pragma unroll
        for (int p = 0; p < 16; ++p) {
            const float v = acc[half][p];
            s += v;
            qq = fmaf(v, v, qq);
            out[(size_t)(b * C3n + o3) * Nn + n0 + ph * 16 + p] = v;
        }
        atomicAdd(&stats3[o3], s);
        atomicAdd(&stats3[C3n + o3], qq);
    }
}

// ---------------------------------------------------------------------------
// K6: in-place BN+relu on d_out
__global__ __launch_bounds__(256) void k_bnout(const float* __restrict__ stats3,
        const float* __restrict__ g3, const float* __restrict__ b3,
        float* __restrict__ out) {
    __shared__ float al[C3n], be[C3n];
    const int tid = threadIdx.x;
    {
        const int ch = tid;
        const float mu  = stats3[ch] * INV_CNT3;
        const float var = stats3[C3n + ch] * INV_CNT3 - mu * mu;
        const float rs  = rsqrtf(var + EPSc);
        al[ch] = rs * g3[ch];
        be[ch] = fmaf(-mu, al[ch], b3[ch]);
    }
    __syncthreads();
    const int total = Bn * C3n * Nn / 4;
    float4* o4 = reinterpret_cast<float4*>(out);
    for (int i = blockIdx.x * 256 + tid; i < total; i += gridDim.x * 256) {
        const int ch = (i >> 10) & 255;
        float4 v = o4[i];
        const float a = al[ch], bb = be[ch];
        v.x = fmaxf(fmaf(v.x, a, bb), 0.0f);
        v.y = fmaxf(fmaf(v.y, a, bb), 0.0f);
        v.z = fmaxf(fmaf(v.z, a, bb), 0.0f);
        v.w = fmaxf(fmaf(v.w, a, bb), 0.0f);
        o4[i] = v;
    }
}

// ---------------------------------------------------------------------------
extern "C" void kernel_launch(void* const* d_in, const int* in_sizes, int n_in,
                              void* d_out, int out_size, void* d_ws, size_t ws_size,
                              hipStream_t stream) {
    const float* x  = (const float*)d_in[0];
    const float* W1 = (const float*)d_in[1];
    const float* g1 = (const float*)d_in[2];
    const float* b1 = (const float*)d_in[3];
    const float* W2 = (const float*)d_in[4];
    const float* g2 = (const float*)d_in[5];
    const float* b2 = (const float*)d_in[6];
    const float* W3 = (const float*)d_in[7];
    const float* g3 = (const float*)d_in[8];
    const float* b3 = (const float*)d_in[9];
    float* out = (float*)d_out;

    int*   idx   = (int*)d_ws;
    float* fws   = (float*)d_ws;
    float* statK = fws + IDX_N;        // 27 used (reserve 64)
    float* Mbuf  = statK + 64;         // 8 * 4096
    float* S64   = Mbuf + 32768;       // 64
    float* AB2   = S64 + 64;           // 256
    float* st3   = AB2 + 256;          // 512
    float* cat   = st3 + 512;          // B*N*192

    k_zero<<<132, 256, 0, stream>>>(statK);
    k_knn<<<dim3(Nn / 32, Bn), 256, 0, stream>>>(x, idx, statK);
    k_conv1<<<Bn * Nn / 32, 256, 0, stream>>>(x, idx, W1, g1, b1, statK, Mbuf, S64, cat);
    k_stats2<<<8, 256, 0, stream>>>(Mbuf, S64, W2, g2, b2, AB2);
    k_conv2<<<Bn * Nn / 8, 256, 0, stream>>>(x, idx, W1, g1, b1, W2, AB2, statK, cat);
    k_fc<<<Bn * Nn / 32, 256, 0, stream>>>(cat, W3, st3, out);
    k_bnout<<<2048, 256, 0, stream>>>(st3, g3, b3, out);
}

// Round 3
// 1437.593 us; speedup vs baseline: 1.0901x; 1.0901x over previous
//
#include <hip/hip_runtime.h>

namespace {
constexpr int Bn  = 8;
constexpr int Nn  = 4096;
constexpr int KKn = 20;
constexpr int C1n = 64;
constexpr int C2n = 128;
constexpr int C3n = 256;
constexpr float EPSc = 1e-5f;
constexpr float INV_CNT1 = 1.0f / (8.0f * 4096.0f * 20.0f);  // B*N*k
constexpr float INV_CNT3 = 1.0f / (8.0f * 4096.0f);          // B*N
constexpr float INFK = 3.0e38f;
constexpr size_t IDX_N = (size_t)Bn * Nn * KKn;              // 655360
}

#define DEVI __device__ __forceinline__

// ---------------------------------------------------------------------------
// K0: zero stat accumulators: statK(64) + Mbuf(8*4096) + S64(64) + AB2(256) + st3(512)
__global__ void k_zero(float* __restrict__ p) {
    const int i = blockIdx.x * 256 + threadIdx.x;
    if (i < 33664) p[i] = 0.0f;
}

// sorted top-3 insert, (d, j) lexicographic
DEVI void ins3(float d, int j, float& m0, float& m1, float& m2,
               int& j0, int& j1, int& j2) {
    if (d < m2) {
        if (d < m1) {
            m2 = m1; j2 = j1;
            if (d < m0) { m1 = m0; j1 = j0; m0 = d; j0 = j; }
            else        { m1 = d;  j1 = j; }
        } else { m2 = d; j2 = j; }
    }
}

// ---------------------------------------------------------------------------
// K1: kNN top-20. 64 lanes per row, TWO rows per wave concurrently (ILP-2 in
// both the scan and the butterfly-extraction chains). Per-lane top-3 + rare
// exact rescan. Batched coalesced idx writeout + channel-independent stats
// (S6 = sum e, M21 = upper(sum e e^T)).
__global__ __launch_bounds__(256) void k_knn(const float* __restrict__ x,
                                             int* __restrict__ idxout,
                                             float* __restrict__ statK) {
    __shared__ float xs[Nn], ys[Nn], zs[Nn];
    __shared__ int   lidx[32][KKn];
    __shared__ float red[4][27];
    const int b = blockIdx.y;
    const float* xb = x + (size_t)b * 3 * Nn;
    for (int t = threadIdx.x; t < Nn; t += 256) {
        xs[t] = xb[t]; ys[t] = xb[Nn + t]; zs[t] = xb[2 * Nn + t];
    }
    const int lane = threadIdx.x & 63;
    const int wave = threadIdx.x >> 6;
    const int rowbase = blockIdx.x * 32 + wave * 8;
    __syncthreads();

    for (int su = 0; su < 4; ++su) {
        const int rA = rowbase + su * 2;
        const int rB = rA + 1;
        const float pxA = xs[rA], pyA = ys[rA], pzA = zs[rA];
        const float pxB = xs[rB], pyB = ys[rB], pzB = zs[rB];
        float mA0 = INFK, mA1 = INFK, mA2 = INFK;
        float mB0 = INFK, mB1 = INFK, mB2 = INFK;
        int jA0 = -1, jA1 = -1, jA2 = -1;
        int jB0 = -1, jB1 = -1, jB2 = -1;
        #pragma unroll 8
        for (int t = 0; t < 64; ++t) {
            const int j = t * 64 + lane;
            const float xj = xs[j], yj = ys[j], zj = zs[j];
            const float dxA = pxA - xj, dyA = pyA - yj, dzA = pzA - zj;
            const float dA = fmaf(dxA, dxA, fmaf(dyA, dyA, dzA * dzA));
            const float dxB = pxB - xj, dyB = pyB - yj, dzB = pzB - zj;
            const float dB = fmaf(dxB, dxB, fmaf(dyB, dyB, dzB * dzB));
            ins3(dA, j, mA0, mA1, mA2, jA0, jA1, jA2);
            ins3(dB, j, mB0, mB1, mB2, jB0, jB1, jB2);
        }
        int nvA = 3, nvB = 3;
        for (int s = 0; s < KKn; ++s) {
            float bdA = (nvA > 0) ? mA0 : INFK;
            int   bjA = (nvA > 0) ? jA0 : -1;
            float bdB = (nvB > 0) ? mB0 : INFK;
            int   bjB = (nvB > 0) ? jB0 : -1;
            #pragma unroll
            for (int off = 32; off; off >>= 1) {
                const float odA = __shfl_xor(bdA, off);
                const int   ojA = __shfl_xor(bjA, off);
                const float odB = __shfl_xor(bdB, off);
                const int   ojB = __shfl_xor(bjB, off);
                if (odA < bdA || (odA == bdA && (unsigned)ojA < (unsigned)bjA)) { bdA = odA; bjA = ojA; }
                if (odB < bdB || (odB == bdB && (unsigned)ojB < (unsigned)bjB)) { bdB = odB; bjB = ojB; }
            }
            if (lane == 0) {
                lidx[wave * 8 + su * 2][s]     = bjA;
                lidx[wave * 8 + su * 2 + 1][s] = bjB;
            }
            // row A: pop / rare rescan
            if (nvA > 0 && jA0 == bjA) {
                mA0 = mA1; jA0 = jA1; mA1 = mA2; jA1 = jA2; --nvA;
                if (nvA == 0 && s < KKn - 1) {
                    mA0 = mA1 = mA2 = INFK; jA0 = jA1 = jA2 = -1;
                    #pragma unroll 1
                    for (int t = 0; t < 64; ++t) {
                        const int j = t * 64 + lane;
                        const float dx = pxA - xs[j], dy = pyA - ys[j], dz = pzA - zs[j];
                        const float d = fmaf(dx, dx, fmaf(dy, dy, dz * dz));
                        if ((d > bdA) || (d == bdA && j > bjA))
                            ins3(d, j, mA0, mA1, mA2, jA0, jA1, jA2);
                    }
                    nvA = 3;
                }
            }
            // row B: pop / rare rescan
            if (nvB > 0 && jB0 == bjB) {
                mB0 = mB1; jB0 = jB1; mB1 = mB2; jB1 = jB2; --nvB;
                if (nvB == 0 && s < KKn - 1) {
                    mB0 = mB1 = mB2 = INFK; jB0 = jB1 = jB2 = -1;
                    #pragma unroll 1
                    for (int t = 0; t < 64; ++t) {
                        const int j = t * 64 + lane;
                        const float dx = pxB - xs[j], dy = pyB - ys[j], dz = pzB - zs[j];
                        const float d = fmaf(dx, dx, fmaf(dy, dy, dz * dz));
                        if ((d > bdB) || (d == bdB && j > bjB))
                            ins3(d, j, mB0, mB1, mB2, jB0, jB1, jB2);
                    }
                    nvB = 3;
                }
            }
        }
    }

    // batched coalesced writeout + stats for this wave's 8 rows (160 winners)
    float S[6] = {};
    float M[21] = {};
    #pragma unroll
    for (int rep = 0; rep < 3; ++rep) {
        const int w = rep * 64 + lane;
        if (w < 8 * KKn) {
            const int r  = (w * 3277) >> 16;        // w / 20 for w < 320
            const int kk = w - r * 20;
            const int rowg = rowbase + r;
            const int j = lidx[wave * 8 + r][kk];
            const float cx = xs[rowg], cy = ys[rowg], cz = zs[rowg];
            const float e[6] = { xs[j] - cx, ys[j] - cy, zs[j] - cz, cx, cy, cz };
            int q = 0;
            #pragma unroll
            for (int a = 0; a < 6; ++a) {
                S[a] += e[a];
                #pragma unroll
                for (int bb = a; bb < 6; ++bb) { M[q] = fmaf(e[a], e[bb], M[q]); ++q; }
            }
            idxout[(size_t)(b * Nn + rowbase) * KKn + w] = j;
        }
    }
    #pragma unroll
    for (int i = 0; i < 6; ++i) {
        float t = S[i];
        #pragma unroll
        for (int off = 1; off < 64; off <<= 1) t += __shfl_xor(t, off);
        S[i] = t;
    }
    #pragma unroll
    for (int i = 0; i < 21; ++i) {
        float t = M[i];
        #pragma unroll
        for (int off = 1; off < 64; off <<= 1) t += __shfl_xor(t, off);
        M[i] = t;
    }
    if (lane == 0) {
        #pragma unroll
        for (int i = 0; i < 6; ++i) red[wave][i] = S[i];
        #pragma unroll
        for (int i = 0; i < 21; ++i) red[wave][6 + i] = M[i];
    }
    __syncthreads();
    if (threadIdx.x < 27) {
        const int i = threadIdx.x;
        atomicAdd(&statK[i], red[0][i] + red[1][i] + red[2][i] + red[3][i]);
    }
}

// ---------------------------------------------------------------------------
// derive BN1 coefficients for channel o from S6/M21
DEVI void bn1_coef(const float* __restrict__ statK, const float* __restrict__ W1,
                   const float* __restrict__ g1, const float* __restrict__ b1,
                   int o, float& a1, float& be1, float* w1r) {
    #pragma unroll
    for (int c = 0; c < 6; ++c) w1r[c] = W1[o * 6 + c];
    float s1 = 0.f, q1 = 0.f;
    #pragma unroll
    for (int a = 0; a < 6; ++a) s1 = fmaf(w1r[a], statK[a], s1);
    int qi = 6;
    #pragma unroll
    for (int a = 0; a < 6; ++a) {
        #pragma unroll
        for (int bb = a; bb < 6; ++bb) {
            const float coef = (a == bb ? 1.f : 2.f) * w1r[a] * w1r[bb];
            q1 = fmaf(coef, statK[qi], q1); ++qi;
        }
    }
    const float mu  = s1 * INV_CNT1;
    const float var = q1 * INV_CNT1 - mu * mu;
    const float rs  = rsqrtf(var + EPSc);
    a1  = rs * g1[o];
    be1 = fmaf(-mu, a1, b1[o]);
}

// shared phase-1: recompute h1_hat for 8 points into LDS [160][64]
template <bool POOL>
DEVI void conv1_phase1(const float* __restrict__ x, const int* __restrict__ idx,
                       float a1, float be1, const float* w1r,
                       float* __restrict__ cat, int b, int n0, int tid,
                       float (*hhat)[64], float* sAcc) {
    const int o = tid & 63;
    const int wave = tid >> 6;
    const float* xb = x + (size_t)b * 3 * Nn;
    #pragma unroll
    for (int pp = 0; pp < 2; ++pp) {
        const int p = wave * 2 + pp;
        const int n = n0 + p;
        const float cx = xb[n], cy = xb[Nn + n], cz = xb[2 * Nn + n];
        const float t2 = fmaf(w1r[3], cx, fmaf(w1r[4], cy, w1r[5] * cz));
        float hk[KKn];
        #pragma unroll
        for (int kk = 0; kk < KKn; ++kk) {
            const int j = idx[(size_t)(b * Nn + n) * KKn + kk];
            const float dx = xb[j] - cx, dy = xb[Nn + j] - cy, dz = xb[2 * Nn + j] - cz;
            float h = fmaf(w1r[0], dx, fmaf(w1r[1], dy, fmaf(w1r[2], dz, t2)));
            h = fmaxf(fmaf(h, a1, be1), 0.0f);
            hk[kk] = h;
            hhat[p * KKn + kk][o] = h;
            if (POOL) *sAcc += h;
        }
        if (POOL) {
            float mx = hk[0];
            #pragma unroll
            for (int kk = 1; kk < KKn; ++kk) mx = fmaxf(mx, hk[kk]);
            float se = 0.0f, sw = 0.0f;
            #pragma unroll
            for (int kk = 0; kk < KKn; ++kk) {
                const float e = __expf(hk[kk] - mx);
                se += e;
                sw = fmaf(hk[kk], e, sw);
            }
            cat[(size_t)(b * Nn + n) * 192 + o] = sw / se;
        }
    }
}

// ---------------------------------------------------------------------------
// K2: phase1 (+x1 pool) over 32 points, accumulate M2 = sum(h h^T) and S64
__global__ __launch_bounds__(256) void k_conv1(const float* __restrict__ x,
        const int* __restrict__ idx,
        const float* __restrict__ W1, const float* __restrict__ g1, const float* __restrict__ b1,
        const float* __restrict__ statK,
        float* __restrict__ Mbuf, float* __restrict__ S64,
        float* __restrict__ cat) {
    __shared__ float hhat[160][64];
    __shared__ float redS[4][64];
    const int tid = threadIdx.x;
    const int b  = blockIdx.x >> 7;
    const int n0 = (blockIdx.x & 127) * 32;
    float a1, be1, w1r[6];
    bn1_coef(statK, W1, g1, b1, tid & 63, a1, be1, w1r);
    const int abase = (tid >> 4) * 4;
    const int bbase = (tid & 15) * 4;
    float acc[4][4] = {};
    float sAcc = 0.f;
    for (int pass = 0; pass < 4; ++pass) {
        if (pass) __syncthreads();
        conv1_phase1<true>(x, idx, a1, be1, w1r, cat, b, n0 + pass * 8, tid, hhat, &sAcc);
        __syncthreads();
        #pragma unroll 2
        for (int p = 0; p < 160; ++p) {
            const float4 hav = *reinterpret_cast<const float4*>(&hhat[p][abase]);
            const float4 hbv = *reinterpret_cast<const float4*>(&hhat[p][bbase]);
            const float ha_[4] = { hav.x, hav.y, hav.z, hav.w };
            const float hb_[4] = { hbv.x, hbv.y, hbv.z, hbv.w };
            #pragma unroll
            for (int i = 0; i < 4; ++i)
                #pragma unroll
                for (int jj = 0; jj < 4; ++jj)
                    acc[i][jj] = fmaf(ha_[i], hb_[jj], acc[i][jj]);
        }
    }
    float* Mb = Mbuf + ((blockIdx.x & 7) << 12);
    #pragma unroll
    for (int i = 0; i < 4; ++i)
        #pragma unroll
        for (int jj = 0; jj < 4; ++jj)
            atomicAdd(&Mb[(abase + i) * 64 + bbase + jj], acc[i][jj]);
    redS[tid >> 6][tid & 63] = sAcc;
    __syncthreads();
    if (tid < 64)
        atomicAdd(&S64[tid], redS[0][tid] + redS[1][tid] + redS[2][tid] + redS[3][tid]);
}

// ---------------------------------------------------------------------------
// K3: finalize conv2 BN coefficients: a2/be2 from W2^T M2 W2 and W2 S64
__global__ __launch_bounds__(256) void k_stats2(const float* __restrict__ Mbuf,
        const float* __restrict__ S64, const float* __restrict__ W2,
        const float* __restrict__ g2, const float* __restrict__ b2,
        float* __restrict__ AB2) {
    __shared__ float ms[4096];
    __shared__ float w2s[16][64];
    const int tid = threadIdx.x;
    for (int e = tid; e < 4096; e += 256) {
        float t = 0.f;
        #pragma unroll
        for (int r = 0; r < 8; ++r) t += Mbuf[r * 4096 + e];
        ms[e] = t;
    }
    const int c0 = blockIdx.x * 16;
    for (int t = tid; t < 16 * 64; t += 256)
        w2s[t >> 6][t & 63] = W2[(c0 + (t >> 6)) * 64 + (t & 63)];
    __syncthreads();
    const int cl = tid >> 4;
    const int gl = tid & 15;
    const int c  = c0 + cl;
    float q2 = 0.f, s2 = 0.f;
    #pragma unroll
    for (int ai = 0; ai < 4; ++ai) {
        const int a = gl * 4 + ai;
        float inner = 0.f;
        for (int bq = 0; bq < 64; ++bq) {
            const int bb = (bq + 4 * gl) & 63;     // rotate to dodge bank conflicts
            inner = fmaf(w2s[cl][bb], ms[a * 64 + bb], inner);
        }
        q2 = fmaf(w2s[cl][a], inner, q2);
        s2 = fmaf(w2s[cl][a], S64[a], s2);
    }
    #pragma unroll
    for (int off = 1; off < 16; off <<= 1) {
        q2 += __shfl_xor(q2, off);
        s2 += __shfl_xor(s2, off);
    }
    if (gl == 0) {
        const float mu  = s2 * INV_CNT1;
        const float var = q2 * INV_CNT1 - mu * mu;
        const float rs  = rsqrtf(var + EPSc);
        const float a2  = rs * g2[c];
        AB2[c]         = a2;
        AB2[C2n + c]   = fmaf(-mu, a2, b2[c]);
    }
}

// ---------------------------------------------------------------------------
// K4: two 8-point groups per block; per group: phase1, then conv2 + BN + relu
// + attn-pool -> cat[:, 64:192]. W2 staged once per block.
__global__ __launch_bounds__(256) void k_conv2(const float* __restrict__ x,
        const int* __restrict__ idx,
        const float* __restrict__ W1, const float* __restrict__ g1, const float* __restrict__ b1,
        const float* __restrict__ W2, const float* __restrict__ AB2,
        const float* __restrict__ statK,
        float* __restrict__ cat) {
    __shared__ float hhat[160][64];
    __shared__ float w2s[C2n][68];
    const int tid = threadIdx.x;
    const int b   = blockIdx.x >> 8;
    const int nb  = (blockIdx.x & 255) * 16;
    float a1, be1, w1r[6];
    bn1_coef(statK, W1, g1, b1, tid & 63, a1, be1, w1r);
    for (int t = tid; t < C2n * C1n; t += 256) w2s[t >> 6][t & 63] = W2[t];

    const int q = tid & 31;
    const int p = tid >> 5;
    float a2[4], be2[4];
    #pragma unroll
    for (int m = 0; m < 4; ++m) {
        const int ch = q + 32 * m;
        a2[m]  = AB2[ch];
        be2[m] = AB2[C2n + ch];
    }

    for (int g = 0; g < 2; ++g) {
        const int n0 = nb + g * 8;
        if (g) __syncthreads();
        conv1_phase1<false>(x, idx, a1, be1, w1r, cat, b, n0, tid, hhat, nullptr);
        __syncthreads();

        const int n = n0 + p;
        float acc[4][KKn] = {};
        for (int oc = 0; oc < 16; ++oc) {
            float4 w[4];
            #pragma unroll
            for (int m = 0; m < 4; ++m)
                w[m] = *reinterpret_cast<const float4*>(&w2s[q + 32 * m][oc * 4]);
            #pragma unroll
            for (int kk = 0; kk < KKn; ++kk) {
                const float4 h = *reinterpret_cast<const float4*>(&hhat[p * KKn + kk][oc * 4]);
                #pragma unroll
                for (int m = 0; m < 4; ++m) {
                    acc[m][kk] = fmaf(w[m].x, h.x, acc[m][kk]);
                    acc[m][kk] = fmaf(w[m].y, h.y, acc[m][kk]);
                    acc[m][kk] = fmaf(w[m].z, h.z, acc[m][kk]);
                    acc[m][kk] = fmaf(w[m].w, h.w, acc[m][kk]);
                }
            }
        }
        #pragma unroll
        for (int m = 0; m < 4; ++m) {
            float v[KKn];
            float mx = 0.0f;
            #pragma unroll
            for (int kk = 0; kk < KKn; ++kk) {
                v[kk] = fmaxf(fmaf(acc[m][kk], a2[m], be2[m]), 0.0f);
                mx = fmaxf(mx, v[kk]);
            }
            float se = 0.0f, sw = 0.0f;
            #pragma unroll
            for (int kk = 0; kk < KKn; ++kk) {
                const float e = __expf(v[kk] - mx);
                se += e;
                sw = fmaf(v[kk], e, sw);
            }
            cat[(size_t)(b * Nn + n) * 192 + 64 + q + 32 * m] = sw / se;
        }
    }
}

// ---------------------------------------------------------------------------
// K5: FC 256<-192 over cat, write pre-BN to d_out, accumulate stats3
__global__ __launch_bounds__(256) void k_fc(const float* __restrict__ cat,
        const float* __restrict__ W3,
        float* __restrict__ stats3, float* __restrict__ out) {
    __shared__ float w3s[C3n][52];
    __shared__ float ctf[32 * 192];
    const int tid = threadIdx.x;
    const int b  = blockIdx.x >> 7;
    const int n0 = (blockIdx.x & 127) * 32;
    const size_t base = (size_t)(b * Nn + n0) * 192;
    for (int t = tid; t < 32 * 192; t += 256) ctf[t] = cat[base + t];
    const int o3a = tid & 127;
    const int ph  = tid >> 7;
    float acc[2][16] = {};
    for (int ch = 0; ch < 4; ++ch) {
        __syncthreads();
        for (int t = tid; t < 256 * 48; t += 256) {
            const int row = t / 48, col = t - row * 48;
            w3s[row][col] = W3[row * 192 + ch * 48 + col];
        }
        __syncthreads();
        for (int c4 = 0; c4 < 12; ++c4) {
            const int c = c4 * 4;
            const float4 wA = *reinterpret_cast<const float4*>(&w3s[o3a][c]);
            const float4 wB = *reinterpret_cast<const float4*>(&w3s[o3a + 128][c]);
            #pragma unroll
            for (int p = 0; p < 16; ++p) {
                const int gp = ph * 16 + p;
                const float4 h = *reinterpret_cast<const float4*>(&ctf[gp * 192 + ch * 48 + c]);
                acc[0][p] = fmaf(wA.x, h.x, acc[0][p]);
                acc[0][p] = fmaf(wA.y, h.y, acc[0][p]);
                acc[0][p] = fmaf(wA.z, h.z, acc[0][p]);
                acc[0][p] = fmaf(wA.w, h.w, acc[0][p]);
                acc[1][p] = fmaf(wB.x, h.x, acc[1][p]);
                acc[1][p] = fmaf(wB.y, h.y, acc[1][p]);
                acc[1][p] = fmaf(wB.z, h.z, acc[1][p]);
                acc[1][p] = fmaf(wB.w, h.w, acc[1][p]);
            }
        }
    }
    #pragma unroll
    for (int half = 0; half < 2; ++half) {
        const int o3 = o3a + half * 128;
        float s = 0.0f, qq = 0.0f;
        #pragma unroll
        for (int p = 0; p < 16; ++p) {
            const float v = acc[half][p];
            s += v;
            qq = fmaf(v, v, qq);
            out[(size_t)(b * C3n + o3) * Nn + n0 + ph * 16 + p] = v;
        }
        atomicAdd(&stats3[o3], s);
        atomicAdd(&stats3[C3n + o3], qq);
    }
}

// ---------------------------------------------------------------------------
// K6: in-place BN+relu on d_out
__global__ __launch_bounds__(256) void k_bnout(const float* __restrict__ stats3,
        const float* __restrict__ g3, const float* __restrict__ b3,
        float* __restrict__ out) {
    __shared__ float al[C3n], be[C3n];
    const int tid = threadIdx.x;
    {
        const int ch = tid;
        const float mu  = stats3[ch] * INV_CNT3;
        const float var = stats3[C3n + ch] * INV_CNT3 - mu * mu;
        const float rs  = rsqrtf(var + EPSc);
        al[ch] = rs * g3[ch];
        be[ch] = fmaf(-mu, al[ch], b3[ch]);
    }
    __syncthreads();
    const int total = Bn * C3n * Nn / 4;
    float4* o4 = reinterpret_cast<float4*>(out);
    for (int i = blockIdx.x * 256 + tid; i < total; i += gridDim.x * 256) {
        const int ch = (i >> 10) & 255;
        float4 v = o4[i];
        const float a = al[ch], bb = be[ch];
        v.x = fmaxf(fmaf(v.x, a, bb), 0.0f);
        v.y = fmaxf(fmaf(v.y, a, bb), 0.0f);
        v.z = fmaxf(fmaf(v.z, a, bb), 0.0f);
        v.w = fmaxf(fmaf(v.w, a, bb), 0.0f);
        o4[i] = v;
    }
}

// ---------------------------------------------------------------------------
extern "C" void kernel_launch(void* const* d_in, const int* in_sizes, int n_in,
                              void* d_out, int out_size, void* d_ws, size_t ws_size,
                              hipStream_t stream) {
    const float* x  = (const float*)d_in[0];
    const float* W1 = (const float*)d_in[1];
    const float* g1 = (const float*)d_in[2];
    const float* b1 = (const float*)d_in[3];
    const float* W2 = (const float*)d_in[4];
    const float* g2 = (const float*)d_in[5];
    const float* b2 = (const float*)d_in[6];
    const float* W3 = (const float*)d_in[7];
    const float* g3 = (const float*)d_in[8];
    const float* b3 = (const float*)d_in[9];
    float* out = (float*)d_out;

    int*   idx   = (int*)d_ws;
    float* fws   = (float*)d_ws;
    float* statK = fws + IDX_N;        // 27 used (reserve 64)
    float* Mbuf  = statK + 64;         // 8 * 4096
    float* S64   = Mbuf + 32768;       // 64
    float* AB2   = S64 + 64;           // 256
    float* st3   = AB2 + 256;          // 512
    float* cat   = st3 + 512;          // B*N*192

    k_zero<<<132, 256, 0, stream>>>(statK);
    k_knn<<<dim3(Nn / 32, Bn), 256, 0, stream>>>(x, idx, statK);
    k_conv1<<<Bn * Nn / 32, 256, 0, stream>>>(x, idx, W1, g1, b1, statK, Mbuf, S64, cat);
    k_stats2<<<8, 256, 0, stream>>>(Mbuf, S64, W2, g2, b2, AB2);
    k_conv2<<<Bn * Nn / 16, 256, 0, stream>>>(x, idx, W1, g1, b1, W2, AB2, statK, cat);
    k_fc<<<Bn * Nn / 32, 256, 0, stream>>>(cat, W3, st3, out);
    k_bnout<<<2048, 256, 0, stream>>>(st3, g3, b3, out);
}

// Round 4
// 1221.593 us; speedup vs baseline: 1.2829x; 1.1768x over previous
//
#include <hip/hip_runtime.h>

namespace {
constexpr int Bn  = 8;
constexpr int Nn  = 4096;
constexpr int KKn = 20;
constexpr int C1n = 64;
constexpr int C2n = 128;
constexpr int C3n = 256;
constexpr float EPSc = 1e-5f;
constexpr float INV_CNT1 = 1.0f / (8.0f * 4096.0f * 20.0f);  // B*N*k
constexpr float INV_CNT3 = 1.0f / (8.0f * 4096.0f);          // B*N
constexpr float INFK = 3.0e38f;
constexpr size_t IDX_N = (size_t)Bn * Nn * KKn;              // 655360
constexpr int NBLK_KNN = (Bn * Nn) / 16;                     // 2048 blocks total
}

#define DEVI __device__ __forceinline__

// ---------------------------------------------------------------------------
// K0: zero stat accumulators: statK(64) + Mbuf(8*4096) + S64(64) + AB2(256) + st3(512)
__global__ void k_zero(float* __restrict__ p) {
    const int i = blockIdx.x * 256 + threadIdx.x;
    if (i < 33664) p[i] = 0.0f;
}

// sorted top-3 insert, (d, j) lexicographic
DEVI void ins3(float d, int j, float& m0, float& m1, float& m2,
               int& j0, int& j1, int& j2) {
    if (d < m2) {
        if (d < m1) {
            m2 = m1; j2 = j1;
            if (d < m0) { m1 = m0; j1 = j0; m0 = d; j0 = j; }
            else        { m1 = d;  j1 = j; }
        } else { m2 = d; j2 = j; }
    }
}

// ---------------------------------------------------------------------------
// K1: kNN top-20. 64 lanes per row, 2 rows concurrently (ILP-2), 4 rows/wave.
// Points read straight from global (L1/L2-resident, coalesced) — NO big LDS,
// so occupancy is ~7 waves/SIMD and the shfl-chain latency overlaps across
// waves. Per-block partial stats written plain (no contended atomics).
__global__ __launch_bounds__(256) void k_knn(const float* __restrict__ x,
                                             int* __restrict__ idxout,
                                             float* __restrict__ Pbuf) {
    __shared__ int   lidx[16][KKn];
    __shared__ float red[4][27];
    const int b = blockIdx.y;
    const float* xb = x + (size_t)b * 3 * Nn;
    const int lane = threadIdx.x & 63;
    const int wave = threadIdx.x >> 6;
    const int rowbase = blockIdx.x * 16 + wave * 4;

    for (int su = 0; su < 2; ++su) {
        const int rA = rowbase + su * 2;
        const int rB = rA + 1;
        const float pxA = xb[rA], pyA = xb[Nn + rA], pzA = xb[2 * Nn + rA];
        const float pxB = xb[rB], pyB = xb[Nn + rB], pzB = xb[2 * Nn + rB];
        float mA0 = INFK, mA1 = INFK, mA2 = INFK;
        float mB0 = INFK, mB1 = INFK, mB2 = INFK;
        int jA0 = -1, jA1 = -1, jA2 = -1;
        int jB0 = -1, jB1 = -1, jB2 = -1;
        #pragma unroll 8
        for (int t = 0; t < 64; ++t) {
            const int j = t * 64 + lane;
            const float xj = xb[j], yj = xb[Nn + j], zj = xb[2 * Nn + j];
            const float dxA = pxA - xj, dyA = pyA - yj, dzA = pzA - zj;
            const float dA = fmaf(dxA, dxA, fmaf(dyA, dyA, dzA * dzA));
            const float dxB = pxB - xj, dyB = pyB - yj, dzB = pzB - zj;
            const float dB = fmaf(dxB, dxB, fmaf(dyB, dyB, dzB * dzB));
            ins3(dA, j, mA0, mA1, mA2, jA0, jA1, jA2);
            ins3(dB, j, mB0, mB1, mB2, jB0, jB1, jB2);
        }
        int nvA = 3, nvB = 3;
        for (int s = 0; s < KKn; ++s) {
            float bdA = (nvA > 0) ? mA0 : INFK;
            int   bjA = (nvA > 0) ? jA0 : -1;
            float bdB = (nvB > 0) ? mB0 : INFK;
            int   bjB = (nvB > 0) ? jB0 : -1;
            #pragma unroll
            for (int off = 32; off; off >>= 1) {
                const float odA = __shfl_xor(bdA, off);
                const int   ojA = __shfl_xor(bjA, off);
                const float odB = __shfl_xor(bdB, off);
                const int   ojB = __shfl_xor(bjB, off);
                if (odA < bdA || (odA == bdA && (unsigned)ojA < (unsigned)bjA)) { bdA = odA; bjA = ojA; }
                if (odB < bdB || (odB == bdB && (unsigned)ojB < (unsigned)bjB)) { bdB = odB; bjB = ojB; }
            }
            if (lane == 0) {
                lidx[wave * 4 + su * 2][s]     = bjA;
                lidx[wave * 4 + su * 2 + 1][s] = bjB;
            }
            // row A: pop / rare rescan
            if (nvA > 0 && jA0 == bjA) {
                mA0 = mA1; jA0 = jA1; mA1 = mA2; jA1 = jA2; --nvA;
                if (nvA == 0 && s < KKn - 1) {
                    mA0 = mA1 = mA2 = INFK; jA0 = jA1 = jA2 = -1;
                    #pragma unroll 1
                    for (int t = 0; t < 64; ++t) {
                        const int j = t * 64 + lane;
                        const float dx = pxA - xb[j], dy = pyA - xb[Nn + j], dz = pzA - xb[2 * Nn + j];
                        const float d = fmaf(dx, dx, fmaf(dy, dy, dz * dz));
                        if ((d > bdA) || (d == bdA && j > bjA))
                            ins3(d, j, mA0, mA1, mA2, jA0, jA1, jA2);
                    }
                    nvA = 3;
                }
            }
            // row B: pop / rare rescan
            if (nvB > 0 && jB0 == bjB) {
                mB0 = mB1; jB0 = jB1; mB1 = mB2; jB1 = jB2; --nvB;
                if (nvB == 0 && s < KKn - 1) {
                    mB0 = mB1 = mB2 = INFK; jB0 = jB1 = jB2 = -1;
                    #pragma unroll 1
                    for (int t = 0; t < 64; ++t) {
                        const int j = t * 64 + lane;
                        const float dx = pxB - xb[j], dy = pyB - xb[Nn + j], dz = pzB - xb[2 * Nn + j];
                        const float d = fmaf(dx, dx, fmaf(dy, dy, dz * dz));
                        if ((d > bdB) || (d == bdB && j > bjB))
                            ins3(d, j, mB0, mB1, mB2, jB0, jB1, jB2);
                    }
                    nvB = 3;
                }
            }
        }
    }
    __syncthreads();

    // batched coalesced writeout + channel-independent stats (80 winners/wave)
    float S[6] = {};
    float M[21] = {};
    #pragma unroll
    for (int rep = 0; rep < 2; ++rep) {
        const int w = rep * 64 + lane;
        if (w < 4 * KKn) {
            const int r  = (w * 3277) >> 16;        // w / 20 for w < 320
            const int kk = w - r * 20;
            const int rowg = rowbase + r;
            const int j = lidx[wave * 4 + r][kk];
            const float cx = xb[rowg], cy = xb[Nn + rowg], cz = xb[2 * Nn + rowg];
            const float e[6] = { xb[j] - cx, xb[Nn + j] - cy, xb[2 * Nn + j] - cz, cx, cy, cz };
            int q = 0;
            #pragma unroll
            for (int a = 0; a < 6; ++a) {
                S[a] += e[a];
                #pragma unroll
                for (int bb = a; bb < 6; ++bb) { M[q] = fmaf(e[a], e[bb], M[q]); ++q; }
            }
            idxout[(size_t)(b * Nn + rowbase) * KKn + w] = j;
        }
    }
    #pragma unroll
    for (int i = 0; i < 6; ++i) {
        float t = S[i];
        #pragma unroll
        for (int off = 1; off < 64; off <<= 1) t += __shfl_xor(t, off);
        S[i] = t;
    }
    #pragma unroll
    for (int i = 0; i < 21; ++i) {
        float t = M[i];
        #pragma unroll
        for (int off = 1; off < 64; off <<= 1) t += __shfl_xor(t, off);
        M[i] = t;
    }
    if (lane == 0) {
        #pragma unroll
        for (int i = 0; i < 6; ++i) red[wave][i] = S[i];
        #pragma unroll
        for (int i = 0; i < 21; ++i) red[wave][6 + i] = M[i];
    }
    __syncthreads();
    if (threadIdx.x < 27) {
        const int i = threadIdx.x;
        const int blk = blockIdx.y * gridDim.x + blockIdx.x;
        Pbuf[blk * 32 + i] = red[0][i] + red[1][i] + red[2][i] + red[3][i];
    }
}

// ---------------------------------------------------------------------------
// K1b: reduce 2048 partial 27-vectors -> statK
__global__ __launch_bounds__(256) void k_statK(const float* __restrict__ Pbuf,
                                               float* __restrict__ statK) {
    __shared__ float red[8][27];
    const int tid = threadIdx.x;
    const int i  = tid & 31;
    const int c0 = tid >> 5;                 // 8 chunks
    if (i < 27) {
        float s = 0.f;
        for (int c = c0; c < NBLK_KNN; c += 8) s += Pbuf[c * 32 + i];
        red[c0][i] = s;
    }
    __syncthreads();
    if (tid < 27) {
        float s = 0.f;
        #pragma unroll
        for (int c = 0; c < 8; ++c) s += red[c][tid];
        statK[tid] = s;
    }
}

// ---------------------------------------------------------------------------
// derive BN1 coefficients for channel o from S6/M21
DEVI void bn1_coef(const float* __restrict__ statK, const float* __restrict__ W1,
                   const float* __restrict__ g1, const float* __restrict__ b1,
                   int o, float& a1, float& be1, float* w1r) {
    #pragma unroll
    for (int c = 0; c < 6; ++c) w1r[c] = W1[o * 6 + c];
    float s1 = 0.f, q1 = 0.f;
    #pragma unroll
    for (int a = 0; a < 6; ++a) s1 = fmaf(w1r[a], statK[a], s1);
    int qi = 6;
    #pragma unroll
    for (int a = 0; a < 6; ++a) {
        #pragma unroll
        for (int bb = a; bb < 6; ++bb) {
            const float coef = (a == bb ? 1.f : 2.f) * w1r[a] * w1r[bb];
            q1 = fmaf(coef, statK[qi], q1); ++qi;
        }
    }
    const float mu  = s1 * INV_CNT1;
    const float var = q1 * INV_CNT1 - mu * mu;
    const float rs  = rsqrtf(var + EPSc);
    a1  = rs * g1[o];
    be1 = fmaf(-mu, a1, b1[o]);
}

// shared phase-1: recompute h1_hat for 8 points into LDS [160][64]
template <bool POOL>
DEVI void conv1_phase1(const float* __restrict__ x, const int* __restrict__ idx,
                       float a1, float be1, const float* w1r,
                       float* __restrict__ cat, int b, int n0, int tid,
                       float (*hhat)[64], float* sAcc) {
    const int o = tid & 63;
    const int wave = tid >> 6;
    const float* xb = x + (size_t)b * 3 * Nn;
    #pragma unroll
    for (int pp = 0; pp < 2; ++pp) {
        const int p = wave * 2 + pp;
        const int n = n0 + p;
        const float cx = xb[n], cy = xb[Nn + n], cz = xb[2 * Nn + n];
        const float t2 = fmaf(w1r[3], cx, fmaf(w1r[4], cy, w1r[5] * cz));
        float hk[KKn];
        #pragma unroll
        for (int kk = 0; kk < KKn; ++kk) {
            const int j = idx[(size_t)(b * Nn + n) * KKn + kk];
            const float dx = xb[j] - cx, dy = xb[Nn + j] - cy, dz = xb[2 * Nn + j] - cz;
            float h = fmaf(w1r[0], dx, fmaf(w1r[1], dy, fmaf(w1r[2], dz, t2)));
            h = fmaxf(fmaf(h, a1, be1), 0.0f);
            hk[kk] = h;
            hhat[p * KKn + kk][o] = h;
            if (POOL) *sAcc += h;
        }
        if (POOL) {
            float mx = hk[0];
            #pragma unroll
            for (int kk = 1; kk < KKn; ++kk) mx = fmaxf(mx, hk[kk]);
            float se = 0.0f, sw = 0.0f;
            #pragma unroll
            for (int kk = 0; kk < KKn; ++kk) {
                const float e = __expf(hk[kk] - mx);
                se += e;
                sw = fmaf(hk[kk], e, sw);
            }
            cat[(size_t)(b * Nn + n) * 192 + o] = sw / se;
        }
    }
}

// ---------------------------------------------------------------------------
// K2: phase1 (+x1 pool) over 32 points, accumulate M2 = sum(h h^T) and S64
__global__ __launch_bounds__(256) void k_conv1(const float* __restrict__ x,
        const int* __restrict__ idx,
        const float* __restrict__ W1, const float* __restrict__ g1, const float* __restrict__ b1,
        const float* __restrict__ statK,
        float* __restrict__ Mbuf, float* __restrict__ S64,
        float* __restrict__ cat) {
    __shared__ float hhat[160][64];
    __shared__ float redS[4][64];
    const int tid = threadIdx.x;
    const int b  = blockIdx.x >> 7;
    const int n0 = (blockIdx.x & 127) * 32;
    float a1, be1, w1r[6];
    bn1_coef(statK, W1, g1, b1, tid & 63, a1, be1, w1r);
    const int abase = (tid >> 4) * 4;
    const int bbase = (tid & 15) * 4;
    float acc[4][4] = {};
    float sAcc = 0.f;
    for (int pass = 0; pass < 4; ++pass) {
        if (pass) __syncthreads();
        conv1_phase1<true>(x, idx, a1, be1, w1r, cat, b, n0 + pass * 8, tid, hhat, &sAcc);
        __syncthreads();
        #pragma unroll 2
        for (int p = 0; p < 160; ++p) {
            const float4 hav = *reinterpret_cast<const float4*>(&hhat[p][abase]);
            const float4 hbv = *reinterpret_cast<const float4*>(&hhat[p][bbase]);
            const float ha_[4] = { hav.x, hav.y, hav.z, hav.w };
            const float hb_[4] = { hbv.x, hbv.y, hbv.z, hbv.w };
            #pragma unroll
            for (int i = 0; i < 4; ++i)
                #pragma unroll
                for (int jj = 0; jj < 4; ++jj)
                    acc[i][jj] = fmaf(ha_[i], hb_[jj], acc[i][jj]);
        }
    }
    float* Mb = Mbuf + ((blockIdx.x & 7) << 12);
    #pragma unroll
    for (int i = 0; i < 4; ++i)
        #pragma unroll
        for (int jj = 0; jj < 4; ++jj)
            atomicAdd(&Mb[(abase + i) * 64 + bbase + jj], acc[i][jj]);
    redS[tid >> 6][tid & 63] = sAcc;
    __syncthreads();
    if (tid < 64)
        atomicAdd(&S64[tid], redS[0][tid] + redS[1][tid] + redS[2][tid] + redS[3][tid]);
}

// ---------------------------------------------------------------------------
// K3: finalize conv2 BN coefficients: a2/be2 from W2^T M2 W2 and W2 S64
__global__ __launch_bounds__(256) void k_stats2(const float* __restrict__ Mbuf,
        const float* __restrict__ S64, const float* __restrict__ W2,
        const float* __restrict__ g2, const float* __restrict__ b2,
        float* __restrict__ AB2) {
    __shared__ float ms[4096];
    __shared__ float w2s[16][64];
    const int tid = threadIdx.x;
    for (int e = tid; e < 4096; e += 256) {
        float t = 0.f;
        #pragma unroll
        for (int r = 0; r < 8; ++r) t += Mbuf[r * 4096 + e];
        ms[e] = t;
    }
    const int c0 = blockIdx.x * 16;
    for (int t = tid; t < 16 * 64; t += 256)
        w2s[t >> 6][t & 63] = W2[(c0 + (t >> 6)) * 64 + (t & 63)];
    __syncthreads();
    const int cl = tid >> 4;
    const int gl = tid & 15;
    const int c  = c0 + cl;
    float q2 = 0.f, s2 = 0.f;
    #pragma unroll
    for (int ai = 0; ai < 4; ++ai) {
        const int a = gl * 4 + ai;
        float inner = 0.f;
        for (int bq = 0; bq < 64; ++bq) {
            const int bb = (bq + 4 * gl) & 63;     // rotate to dodge bank conflicts
            inner = fmaf(w2s[cl][bb], ms[a * 64 + bb], inner);
        }
        q2 = fmaf(w2s[cl][a], inner, q2);
        s2 = fmaf(w2s[cl][a], S64[a], s2);
    }
    #pragma unroll
    for (int off = 1; off < 16; off <<= 1) {
        q2 += __shfl_xor(q2, off);
        s2 += __shfl_xor(s2, off);
    }
    if (gl == 0) {
        const float mu  = s2 * INV_CNT1;
        const float var = q2 * INV_CNT1 - mu * mu;
        const float rs  = rsqrtf(var + EPSc);
        const float a2  = rs * g2[c];
        AB2[c]         = a2;
        AB2[C2n + c]   = fmaf(-mu, a2, b2[c]);
    }
}

// ---------------------------------------------------------------------------
// K4: two 8-point groups per block; per group: phase1, then conv2 + BN + relu
// + attn-pool -> cat[:, 64:192]. W2 staged once per block.
__global__ __launch_bounds__(256) void k_conv2(const float* __restrict__ x,
        const int* __restrict__ idx,
        const float* __restrict__ W1, const float* __restrict__ g1, const float* __restrict__ b1,
        const float* __restrict__ W2, const float* __restrict__ AB2,
        const float* __restrict__ statK,
        float* __restrict__ cat) {
    __shared__ float hhat[160][64];
    __shared__ float w2s[C2n][68];
    const int tid = threadIdx.x;
    const int b   = blockIdx.x >> 8;
    const int nb  = (blockIdx.x & 255) * 16;
    float a1, be1, w1r[6];
    bn1_coef(statK, W1, g1, b1, tid & 63, a1, be1, w1r);
    for (int t = tid; t < C2n * C1n; t += 256) w2s[t >> 6][t & 63] = W2[t];

    const int q = tid & 31;
    const int p = tid >> 5;
    float a2[4], be2[4];
    #pragma unroll
    for (int m = 0; m < 4; ++m) {
        const int ch = q + 32 * m;
        a2[m]  = AB2[ch];
        be2[m] = AB2[C2n + ch];
    }

    for (int g = 0; g < 2; ++g) {
        const int n0 = nb + g * 8;
        if (g) __syncthreads();
        conv1_phase1<false>(x, idx, a1, be1, w1r, cat, b, n0, tid, hhat, nullptr);
        __syncthreads();

        const int n = n0 + p;
        float acc[4][KKn] = {};
        for (int oc = 0; oc < 16; ++oc) {
            float4 w[4];
            #pragma unroll
            for (int m = 0; m < 4; ++m)
                w[m] = *reinterpret_cast<const float4*>(&w2s[q + 32 * m][oc * 4]);
            #pragma unroll
            for (int kk = 0; kk < KKn; ++kk) {
                const float4 h = *reinterpret_cast<const float4*>(&hhat[p * KKn + kk][oc * 4]);
                #pragma unroll
                for (int m = 0; m < 4; ++m) {
                    acc[m][kk] = fmaf(w[m].x, h.x, acc[m][kk]);
                    acc[m][kk] = fmaf(w[m].y, h.y, acc[m][kk]);
                    acc[m][kk] = fmaf(w[m].z, h.z, acc[m][kk]);
                    acc[m][kk] = fmaf(w[m].w, h.w, acc[m][kk]);
                }
            }
        }
        #pragma unroll
        for (int m = 0; m < 4; ++m) {
            float v[KKn];
            float mx = 0.0f;
            #pragma unroll
            for (int kk = 0; kk < KKn; ++kk) {
                v[kk] = fmaxf(fmaf(acc[m][kk], a2[m], be2[m]), 0.0f);
                mx = fmaxf(mx, v[kk]);
            }
            float se = 0.0f, sw = 0.0f;
            #pragma unroll
            for (int kk = 0; kk < KKn; ++kk) {
                const float e = __expf(v[kk] - mx);
                se += e;
                sw = fmaf(v[kk], e, sw);
            }
            cat[(size_t)(b * Nn + n) * 192 + 64 + q + 32 * m] = sw / se;
        }
    }
}

// ---------------------------------------------------------------------------
// K5: FC 256<-192 over cat, write pre-BN to d_out, accumulate stats3
__global__ __launch_bounds__(256) void k_fc(const float* __restrict__ cat,
        const float* __restrict__ W3,
        float* __restrict__ stats3, float* __restrict__ out) {
    __shared__ float w3s[C3n][52];
    __shared__ float ctf[32 * 192];
    const int tid = threadIdx.x;
    const int b  = blockIdx.x >> 7;
    const int n0 = (blockIdx.x & 127) * 32;
    const size_t base = (size_t)(b * Nn + n0) * 192;
    for (int t = tid; t < 32 * 192; t += 256) ctf[t] = cat[base + t];
    const int o3a = tid & 127;
    const int ph  = tid >> 7;
    float acc[2][16] = {};
    for (int ch = 0; ch < 4; ++ch) {
        __syncthreads();
        for (int t = tid; t < 256 * 48; t += 256) {
            const int row = t / 48, col = t - row * 48;
            w3s[row][col] = W3[row * 192 + ch * 48 + col];
        }
        __syncthreads();
        for (int c4 = 0; c4 < 12; ++c4) {
            const int c = c4 * 4;
            const float4 wA = *reinterpret_cast<const float4*>(&w3s[o3a][c]);
            const float4 wB = *reinterpret_cast<const float4*>(&w3s[o3a + 128][c]);
            #pragma unroll
            for (int p = 0; p < 16; ++p) {
                const int gp = ph * 16 + p;
                const float4 h = *reinterpret_cast<const float4*>(&ctf[gp * 192 + ch * 48 + c]);
                acc[0][p] = fmaf(wA.x, h.x, acc[0][p]);
                acc[0][p] = fmaf(wA.y, h.y, acc[0][p]);
                acc[0][p] = fmaf(wA.z, h.z, acc[0][p]);
                acc[0][p] = fmaf(wA.w, h.w, acc[0][p]);
                acc[1][p] = fmaf(wB.x, h.x, acc[1][p]);
                acc[1][p] = fmaf(wB.y, h.y, acc[1][p]);
                acc[1][p] = fmaf(wB.z, h.z, acc[1][p]);
                acc[1][p] = fmaf(wB.w, h.w, acc[1][p]);
            }
        }
    }
    #pragma unroll
    for (int half = 0; half < 2; ++half) {
        const int o3 = o3a + half * 128;
        float s = 0.0f, qq = 0.0f;
        #pragma unroll
        for (int p = 0; p < 16; ++p) {
            const float v = acc[half][p];
            s += v;
            qq = fmaf(v, v, qq);
            out[(size_t)(b * C3n + o3) * Nn + n0 + ph * 16 + p] = v;
        }
        atomicAdd(&stats3[o3], s);
        atomicAdd(&stats3[C3n + o3], qq);
    }
}

// ---------------------------------------------------------------------------
// K6: in-place BN+relu on d_out
__global__ __launch_bounds__(256) void k_bnout(const float* __restrict__ stats3,
        const float* __restrict__ g3, const float* __restrict__ b3,
        float* __restrict__ out) {
    __shared__ float al[C3n], be[C3n];
    const int tid = threadIdx.x;
    {
        const int ch = tid;
        const float mu  = stats3[ch] * INV_CNT3;
        const float var = stats3[C3n + ch] * INV_CNT3 - mu * mu;
        const float rs  = rsqrtf(var + EPSc);
        al[ch] = rs * g3[ch];
        be[ch] = fmaf(-mu, al[ch], b3[ch]);
    }
    __syncthreads();
    const int total = Bn * C3n * Nn / 4;
    float4* o4 = reinterpret_cast<float4*>(out);
    for (int i = blockIdx.x * 256 + tid; i < total; i += gridDim.x * 256) {
        const int ch = (i >> 10) & 255;
        float4 v = o4[i];
        const float a = al[ch], bb = be[ch];
        v.x = fmaxf(fmaf(v.x, a, bb), 0.0f);
        v.y = fmaxf(fmaf(v.y, a, bb), 0.0f);
        v.z = fmaxf(fmaf(v.z, a, bb), 0.0f);
        v.w = fmaxf(fmaf(v.w, a, bb), 0.0f);
        o4[i] = v;
    }
}

// ---------------------------------------------------------------------------
extern "C" void kernel_launch(void* const* d_in, const int* in_sizes, int n_in,
                              void* d_out, int out_size, void* d_ws, size_t ws_size,
                              hipStream_t stream) {
    const float* x  = (const float*)d_in[0];
    const float* W1 = (const float*)d_in[1];
    const float* g1 = (const float*)d_in[2];
    const float* b1 = (const float*)d_in[3];
    const float* W2 = (const float*)d_in[4];
    const float* g2 = (const float*)d_in[5];
    const float* b2 = (const float*)d_in[6];
    const float* W3 = (const float*)d_in[7];
    const float* g3 = (const float*)d_in[8];
    const float* b3 = (const float*)d_in[9];
    float* out = (float*)d_out;

    int*   idx   = (int*)d_ws;
    float* fws   = (float*)d_ws;
    float* statK = fws + IDX_N;        // 27 used (reserve 64)
    float* Mbuf  = statK + 64;         // 8 * 4096
    float* S64   = Mbuf + 32768;       // 64
    float* AB2   = S64 + 64;           // 256
    float* st3   = AB2 + 256;          // 512
    float* cat   = st3 + 512;          // B*N*192
    float* Pbuf  = cat;                // aliases cat head (2048*32 floats);
                                       // consumed by k_statK before cat is written

    k_zero<<<132, 256, 0, stream>>>(statK);
    k_knn<<<dim3(Nn / 16, Bn), 256, 0, stream>>>(x, idx, Pbuf);
    k_statK<<<1, 256, 0, stream>>>(Pbuf, statK);
    k_conv1<<<Bn * Nn / 32, 256, 0, stream>>>(x, idx, W1, g1, b1, statK, Mbuf, S64, cat);
    k_stats2<<<8, 256, 0, stream>>>(Mbuf, S64, W2, g2, b2, AB2);
    k_conv2<<<Bn * Nn / 16, 256, 0, stream>>>(x, idx, W1, g1, b1, W2, AB2, statK, cat);
    k_fc<<<Bn * Nn / 32, 256, 0, stream>>>(cat, W3, st3, out);
    k_bnout<<<2048, 256, 0, stream>>>(st3, g3, b3, out);
}